// Round 15
// baseline (148.261 us; speedup 1.0000x reference)
//
#include <hip/hip_runtime.h>
#include <math.h>

typedef _Float16 h2_t __attribute__((ext_vector_type(2)));
typedef _Float16 h4_t __attribute__((ext_vector_type(4)));
typedef _Float16 h8_t __attribute__((ext_vector_type(8)));

#define NP 32
#define KC 31
#define HH 512
#define WW 512
#define BB 4
#define CC 3

#define TXO 64        // 64-wide tile
#define TYO 8         // 8 output rows -> 128-thread (2-wave) block
#define NT 128        // threads per block
#define TROWS 38      // 8 outputs + 15 + 15 halo
#define TWORDS 48     // row stride in h2 words (16-lane quarter-wave covers
                      // all 32 banks exactly once -> conflict-free b64)
#define TILEW (TROWS * TWORDS)   // 1824 h2 words, ONE channel at a time
#define WSTR 36       // weight table plane stride in h2 words

// HARD CONSTRAINTS (measured R0-R12):
//  - grid z = BB; wj[64] -> VGPR cap >=128 (R7: cap 64 -> 158MB spill).
//  - NOTHING long-lived across the compute loop beyond pipeline buffers.
//  - Scheduling arc DEAD (R9=R11=70us); DS/VALU group-pinning POISON (R10).
//  - LDS capacity NOT the residency cap (R12: 31->14KB, occupancy flat 18.5%).
//  - Occupancy correlates ONLY with VGPR across 13 rounds (64->43%, 116->18.5%);
//    VGPR<=64 unreachable with wj[64] resident -> that lever is closed.
//  - Duration = VALU + LDS (sum, not max): phase-locked waves convoy
//    (identical step lengths + intra-block barriers align 4-wave blocks).
// R13/R14: broker/container failed twice (no dispatch data; kernel audited
// clean: no OOB, no hangs, same compile complexity as R12). THIRD attempt,
// unchanged. If infra fails again -> next round submits byte-identical R12
// as the infra-vs-kernel disambiguator.
// HYPOTHESIS: TYO 16->8: 2-wave blocks, 8 independent blocks/CU (8 phase
// domains vs 4), same 16-wave/CU grid cap, same per-thread work.
// Cost: halo ratio -> FETCH ~13.7->22MB (~+2us).

__device__ __forceinline__ double plane_of(int i) {
    const double stepd = 50.0 / 31.0;
    return (i < 31) ? (double)i * stepd : 50.0;
}

__device__ __forceinline__ h2_t mkh2(_Float16 a, _Float16 b) {
    h2_t r; r.x = a; r.y = b; return r;
}

__launch_bounds__(128, 2)
__global__ void defocus_kernel(const float* __restrict__ img,
                               const float* __restrict__ coc,
                               float* __restrict__ out) {
    const int tx = threadIdx.x;            // 0..15
    const int ty = threadIdx.y;            // 0..7
    const int tid = ty * 16 + tx;
    const int tilex = blockIdx.x * TXO;
    const int tiley = blockIdx.y * TYO;
    const int b = blockIdx.z;

    __shared__ __align__(16) h2_t wtab[NP * WSTR];   // 4608 B
    __shared__ __align__(16) h2_t tile[TILEW];       // 3648 B  (total ~8.3 KB)

    const int yo = tiley + ty;
    const int xo = tilex + tx * 4;

    // ---- (1) coc load first; its latency hides under the wtab build
    const float4 cv = *(const float4*)&coc[((size_t)b * HH + yo) * WW + xo];

    // ---- (2) in-block wtab build (bit-identical values; 8 passes x 4 planes
    //          for the 128-thread block; same per-plane 32-lane groups).
    {
        const int t = tid & 31;               // padded tap position 0..31
        #pragma unroll
        for (int pass = 0; pass < 8; ++pass) {
            const int p = (tid >> 5) + 4 * pass;    // plane 0..31
            const double stepd = 50.0 / 31.0;
            double cocp = (p < 31) ? (double)p * stepd : 50.0;  // numpy linspace
            float gt;
            if (cocp < 0.5) {
                gt = (t == 15) ? 1.f : 0.f;   // identity plane (plane 0 only)
            } else {
                double sigma = cocp / 2.355;
                int k = (int)(2.0 * cocp + 1.0);   // trunc, matches python int()
                if ((k & 1) == 0) k += 1;
                if (k > KC) k = KC;
                int h = k / 2;
                int d = t - 15;
                float denom = (float)(2.0 * sigma * sigma);
                float v = (d >= -h && d <= h && t < KC) ? expf(-(float)(d * d) / denom) : 0.f;
                float s = v;
                #pragma unroll
                for (int off = 1; off < 32; off <<= 1) s += __shfl_xor(s, off, 32);
                gt = v / s;
            }
            const int m = t & 15;
            const int s0 = (t < 16) ? (2 * m) : ((2 * m - 1 < 0) ? 0 : 2 * m - 1);
            const int s1 = (t < 16) ? (2 * m + 1) : (2 * m);
            float w0 = __shfl(gt, s0, 32);
            float w1 = __shfl(gt, s1, 32);
            if (t >= 16 && (2 * m - 1) < 0) w0 = 0.f;   // g[-1] = 0
            h2_t w; w.x = (_Float16)w0; w.y = (_Float16)w1;
            wtab[p * WSTR + t] = w;
            if (t < WSTR - 32) {
                h2_t z; z.x = (_Float16)0.f; z.y = (_Float16)0.f;
                wtab[p * WSTR + 32 + t] = z;
            }
        }
    }

    // ---- (3) per-pixel bin index, exact double-precision boundary semantics
    const float cocf[4] = {cv.x, cv.y, cv.z, cv.w};
    int idx[4];
    #pragma unroll
    for (int j = 0; j < 4; ++j) {
        const double stepd = 50.0 / 31.0;
        double cd = (double)cocf[j];
        int i0 = (int)floor(cd / stepd + 0.5);
        i0 = min(max(i0, 0), 31);
        if (i0 > 0 && cd <= 0.5 * (plane_of(i0 - 1) + plane_of(i0))) {
            i0 -= 1;
        } else if (i0 < 31 && cd > 0.5 * (plane_of(i0) + plane_of(i0 + 1))) {
            i0 += 1;
        }
        idx[j] = i0;
    }

    // Fence: forbid hoisting staging loads up across the f64 region (R1 spill).
    __builtin_amdgcn_sched_barrier(0);

    // ---- (4) stage channel 0
    {
        const float* src = img + (size_t)(b * CC) * HH * WW;
        for (int f = tid; f < TILEW; f += NT) {
            int r = f / TWORDS;
            int w = f - r * TWORDS;
            int gy = tiley - 15 + r;
            int gx = tilex - 15 + 2 * w;
            float v0 = 0.f, v1 = 0.f;
            if ((unsigned)gy < (unsigned)HH) {
                if ((unsigned)gx < (unsigned)WW) v0 = src[gy * WW + gx];
                if ((unsigned)(gx + 1) < (unsigned)WW) v1 = src[gy * WW + gx + 1];
            }
            h2_t pv; pv.x = (_Float16)v0; pv.y = (_Float16)v1;
            tile[f] = pv;
        }
    }

    __syncthreads();   // wtab + tile(ch0) staged

    // ---- (5) gather this thread's 4 weight rows into registers
    // even local col (j=0,2): phase A; odd (j=1,3): phase B (pre-shifted one tap)
    h2_t wj[4][16];
    #pragma unroll
    for (int j = 0; j < 4; ++j) {
        const h2_t* wp = &wtab[idx[j] * WSTR + (j & 1) * 16];
        #pragma unroll
        for (int m = 0; m < 4; ++m) {
            h8_t v = *(const h8_t*)(wp + 4 * m);   // 16B aligned: WSTR%4==0
            #pragma unroll
            for (int q = 0; q < 4; ++q) {
                h2_t t2; t2.x = v[2 * q]; t2.y = v[2 * q + 1];
                wj[j][4 * m + q] = t2;
            }
        }
    }

// word I (h2) view of a folded h4 buffer F[9] -- pure register aliasing
#define RWW(F, I) mkh2(F[(I) >> 1][((I) & 1) * 2], F[(I) >> 1][((I) & 1) * 2 + 1])

// issue one row's 9 ds_read_b64 into an h4 buffer
#define ISSUE_ROW(DST, ROW)                                                  \
    {                                                                        \
        _Pragma("unroll")                                                    \
        for (int m = 0; m < 9; ++m)                                          \
            DST[m] = *(const h4_t*)(rowbase + (ROW) * TWORDS + 2 * m);       \
    }

#define ISSUE_PAIR(QA, QB, D)                                                \
    ISSUE_ROW(QA, 15 - (D))                                                  \
    ISSUE_ROW(QB, 15 + (D))

// in-place fold: QA[m] += QB[m]  (2x v_pk_add_f16 each; QA becomes the row)
#define FOLD(QA, QB)                                                         \
    {                                                                        \
        _Pragma("unroll")                                                    \
        for (int m = 0; m < 9; ++m) QA[m] = QA[m] + QB[m];                   \
    }

// horizontal dot on folded buffer F (words 0..16 used; rs2/3 shifted by 1)
#define HDOTF(F, RS0, RS1, RS2, RS3)                                         \
    {                                                                        \
        _Pragma("unroll")                                                    \
        for (int m = 0; m < 16; ++m) {                                       \
            RS0 = __builtin_amdgcn_fdot2(wj[0][m], RWW(F, m),     RS0, false);\
            RS1 = __builtin_amdgcn_fdot2(wj[1][m], RWW(F, m),     RS1, false);\
            RS2 = __builtin_amdgcn_fdot2(wj[2][m], RWW(F, m + 1), RS2, false);\
            RS3 = __builtin_amdgcn_fdot2(wj[3][m], RWW(F, m + 1), RS3, false);\
        }                                                                    \
    }

// column-weight extraction for compile-time DY (verified phase mapping)
#define CWEXT(DY, CW0, CW1, CW2, CW3)                                        \
    {                                                                        \
        if (((DY) & 1) == 0) {                                               \
            CW0 = (float)wj[0][(DY) >> 1].x;                                 \
            CW2 = (float)wj[2][(DY) >> 1].x;                                 \
            CW1 = (float)wj[1][(DY) >> 1].y;                                 \
            CW3 = (float)wj[3][(DY) >> 1].y;                                 \
        } else {                                                             \
            CW0 = (float)wj[0][(DY) >> 1].y;                                 \
            CW2 = (float)wj[2][(DY) >> 1].y;                                 \
            CW1 = (float)wj[1][((DY) + 1) >> 1].x;                           \
            CW3 = (float)wj[3][((DY) + 1) >> 1].x;                           \
        }                                                                    \
    }

// pipeline step for pair D: fold cur, issue pair D+1, hdot cur (no fences)
#define STEP(D, CQA, CQB, NQA, NQB, DOISSUE)                                 \
    {                                                                        \
        FOLD(CQA, CQB)                                                       \
        if (DOISSUE) { ISSUE_PAIR(NQA, NQB, (D) + 1) }                       \
        float rs0 = 0.f, rs1 = 0.f, rs2 = 0.f, rs3 = 0.f;                    \
        HDOTF(CQA, rs0, rs1, rs2, rs3)                                       \
        float cw0, cw1, cw2, cw3;                                            \
        CWEXT(15 - (D), cw0, cw1, cw2, cw3)                                  \
        acc0 += cw0 * rs0;  acc1 += cw1 * rs1;                               \
        acc2 += cw2 * rs2;  acc3 += cw3 * rs3;                               \
    }

    // ---- (6) per-channel: compute c (pipelined dy-loop), then stage c+1
    #pragma unroll 1
    for (int c = 0; c < CC; ++c) {
        float acc0 = 0.f, acc1 = 0.f, acc2 = 0.f, acc3 = 0.f;
        const h2_t* rowbase = &tile[ty * TWORDS + 2 * tx];

        h4_t Aqa[9], Aqb[9], Bqa[9], Bqb[9];

        // prologue: center row reads + pair-1 reads in flight
        ISSUE_ROW(Aqa, 15)
        ISSUE_PAIR(Bqa, Bqb, 1)

        // center row (dy = 15): no fold, waits only on Aqa's 9 reads
        {
            float rs0 = 0.f, rs1 = 0.f, rs2 = 0.f, rs3 = 0.f;
            HDOTF(Aqa, rs0, rs1, rs2, rs3)
            float cw0, cw1, cw2, cw3;
            CWEXT(15, cw0, cw1, cw2, cw3)
            acc0 += cw0 * rs0;  acc1 += cw1 * rs1;
            acc2 += cw2 * rs2;  acc3 += cw3 * rs3;
        }

        STEP(1,  Bqa, Bqb, Aqa, Aqb, 1)
        STEP(2,  Aqa, Aqb, Bqa, Bqb, 1)
        STEP(3,  Bqa, Bqb, Aqa, Aqb, 1)
        STEP(4,  Aqa, Aqb, Bqa, Bqb, 1)
        STEP(5,  Bqa, Bqb, Aqa, Aqb, 1)
        STEP(6,  Aqa, Aqb, Bqa, Bqb, 1)
        STEP(7,  Bqa, Bqb, Aqa, Aqb, 1)
        STEP(8,  Aqa, Aqb, Bqa, Bqb, 1)
        STEP(9,  Bqa, Bqb, Aqa, Aqb, 1)
        STEP(10, Aqa, Aqb, Bqa, Bqb, 1)
        STEP(11, Bqa, Bqb, Aqa, Aqb, 1)
        STEP(12, Aqa, Aqb, Bqa, Bqb, 1)
        STEP(13, Bqa, Bqb, Aqa, Aqb, 1)
        STEP(14, Aqa, Aqb, Bqa, Bqb, 1)
        STEP(15, Bqa, Bqb, Aqa, Aqb, 0)

        *(float4*)&out[((size_t)(b * CC + c) * HH + yo) * WW + xo] =
            make_float4(acc0, acc1, acc2, acc3);

        if (c + 1 < CC) {
            __syncthreads();   // this channel's readers done
            const float* src = img + (size_t)(b * CC + c + 1) * HH * WW;
            for (int f = tid; f < TILEW; f += NT) {
                int r = f / TWORDS;
                int w = f - r * TWORDS;
                int gy = tiley - 15 + r;
                int gx = tilex - 15 + 2 * w;
                float v0 = 0.f, v1 = 0.f;
                if ((unsigned)gy < (unsigned)HH) {
                    if ((unsigned)gx < (unsigned)WW) v0 = src[gy * WW + gx];
                    if ((unsigned)(gx + 1) < (unsigned)WW) v1 = src[gy * WW + gx + 1];
                }
                h2_t pv; pv.x = (_Float16)v0; pv.y = (_Float16)v1;
                tile[f] = pv;
            }
            __syncthreads();   // tile(c+1) ready
        }
    }

#undef RWW
#undef ISSUE_ROW
#undef ISSUE_PAIR
#undef FOLD
#undef HDOTF
#undef CWEXT
#undef STEP
}

extern "C" void kernel_launch(void* const* d_in, const int* in_sizes, int n_in,
                              void* d_out, int out_size, void* d_ws, size_t ws_size,
                              hipStream_t stream) {
    const float* sharp = (const float*)d_in[0];
    const float* cocm  = (const float*)d_in[1];
    float* out = (float*)d_out;

    dim3 grid(WW / TXO, HH / TYO, BB);   // 8 x 64 x 4 = 2048 blocks
    dim3 block(16, 8, 1);
    defocus_kernel<<<grid, block, 0, stream>>>(sharp, cocm, out);
}

// Round 16
// 121.280 us; speedup vs baseline: 1.2225x; 1.2225x over previous
//
#include <hip/hip_runtime.h>
#include <math.h>

typedef _Float16 h2_t __attribute__((ext_vector_type(2)));
typedef _Float16 h4_t __attribute__((ext_vector_type(4)));
typedef _Float16 h8_t __attribute__((ext_vector_type(8)));

#define NP 32
#define KC 31
#define HH 512
#define WW 512
#define BB 4
#define CC 3

#define TXO 64        // 64-wide tile
#define TYO 16        // 16 output rows -> 256-thread block (measured optimum)
#define NT 256        // threads per block
#define TROWS 46      // 16 outputs + 15 + 15 halo
#define TWORDS 48     // row stride in h2 words (4ty x 16tx quarter-wave covers
                      // all 32 banks exactly once -> conflict-free b64)
#define TILEW (TROWS * TWORDS)   // 2208 h2 words, ONE channel at a time
#define WSTR 36       // weight table plane stride in h2 words

// FINAL KERNEL = R12 (session best: 68.4us kernel, 122.4us bench, vs 136.3
// baseline). Restored after R15's TYO=8 probe regressed (97.8us: per-block
// overhead amortization halved, no occupancy gain).
// CLOSED LEVERS (all measured):
//  - VGPR cap >=128 required (R7: cap 64 -> 158MB spill); wj[4][16]=64 regs
//    is irreducible (fewer outputs/thread doubles LDS traffic: same 17-word
//    window); nothing register-live across the dy-loop (R1/R2/R3 spills).
//  - Scheduling: fence = no-fence (R9=R11); DS/VALU sched_group pinning is
//    POISON (R10: bank conflicts 1.02M->6.5M); compiler schedule is optimal.
//  - VALU count: symmetric fold cut fdot2 48% with ZERO duration change (R6).
//  - LDS capacity not the residency cap (R12: 31->14KB, occupancy flat).
//  - Block size: 512t=85us, 256t=68us, 128t=98us. 256 is the optimum.
//  - Residual: both pipes ~50% busy, duration = VALU+LDS (sum not max);
//    residency pinned ~6 waves/CU at VGPR>=100 across ALL structures.
//    No remaining source-level lever identified after 15 rounds.

__device__ __forceinline__ double plane_of(int i) {
    const double stepd = 50.0 / 31.0;
    return (i < 31) ? (double)i * stepd : 50.0;
}

__device__ __forceinline__ h2_t mkh2(_Float16 a, _Float16 b) {
    h2_t r; r.x = a; r.y = b; return r;
}

__launch_bounds__(256, 2)
__global__ void defocus_kernel(const float* __restrict__ img,
                               const float* __restrict__ coc,
                               float* __restrict__ out) {
    const int tx = threadIdx.x;            // 0..15
    const int ty = threadIdx.y;            // 0..15
    const int tid = ty * 16 + tx;
    const int tilex = blockIdx.x * TXO;
    const int tiley = blockIdx.y * TYO;
    const int b = blockIdx.z;

    __shared__ __align__(16) h2_t wtab[NP * WSTR];   // 4608 B
    __shared__ __align__(16) h2_t tile[TILEW];       // 4416 B  (total ~9.0 KB)

    const int yo = tiley + ty;
    const int xo = tilex + tx * 4;

    // ---- (1) coc load first; its latency hides under the wtab build
    const float4 cv = *(const float4*)&coc[((size_t)b * HH + yo) * WW + xo];

    // ---- (2) in-block wtab build (bit-identical values; 4 passes x 8 planes).
    {
        const int t = tid & 31;               // padded tap position 0..31
        #pragma unroll
        for (int pass = 0; pass < 4; ++pass) {
            const int p = (tid >> 5) + 8 * pass;    // plane 0..31
            const double stepd = 50.0 / 31.0;
            double cocp = (p < 31) ? (double)p * stepd : 50.0;  // numpy linspace
            float gt;
            if (cocp < 0.5) {
                gt = (t == 15) ? 1.f : 0.f;   // identity plane (plane 0 only)
            } else {
                double sigma = cocp / 2.355;
                int k = (int)(2.0 * cocp + 1.0);   // trunc, matches python int()
                if ((k & 1) == 0) k += 1;
                if (k > KC) k = KC;
                int h = k / 2;
                int d = t - 15;
                float denom = (float)(2.0 * sigma * sigma);
                float v = (d >= -h && d <= h && t < KC) ? expf(-(float)(d * d) / denom) : 0.f;
                float s = v;
                #pragma unroll
                for (int off = 1; off < 32; off <<= 1) s += __shfl_xor(s, off, 32);
                gt = v / s;
            }
            const int m = t & 15;
            const int s0 = (t < 16) ? (2 * m) : ((2 * m - 1 < 0) ? 0 : 2 * m - 1);
            const int s1 = (t < 16) ? (2 * m + 1) : (2 * m);
            float w0 = __shfl(gt, s0, 32);
            float w1 = __shfl(gt, s1, 32);
            if (t >= 16 && (2 * m - 1) < 0) w0 = 0.f;   // g[-1] = 0
            h2_t w; w.x = (_Float16)w0; w.y = (_Float16)w1;
            wtab[p * WSTR + t] = w;
            if (t < WSTR - 32) {
                h2_t z; z.x = (_Float16)0.f; z.y = (_Float16)0.f;
                wtab[p * WSTR + 32 + t] = z;
            }
        }
    }

    // ---- (3) per-pixel bin index, exact double-precision boundary semantics
    const float cocf[4] = {cv.x, cv.y, cv.z, cv.w};
    int idx[4];
    #pragma unroll
    for (int j = 0; j < 4; ++j) {
        const double stepd = 50.0 / 31.0;
        double cd = (double)cocf[j];
        int i0 = (int)floor(cd / stepd + 0.5);
        i0 = min(max(i0, 0), 31);
        if (i0 > 0 && cd <= 0.5 * (plane_of(i0 - 1) + plane_of(i0))) {
            i0 -= 1;
        } else if (i0 < 31 && cd > 0.5 * (plane_of(i0) + plane_of(i0 + 1))) {
            i0 += 1;
        }
        idx[j] = i0;
    }

    // Fence: forbid hoisting staging loads up across the f64 region (R1 spill).
    __builtin_amdgcn_sched_barrier(0);

    // ---- (4) stage channel 0
    {
        const float* src = img + (size_t)(b * CC) * HH * WW;
        for (int f = tid; f < TILEW; f += NT) {
            int r = f / TWORDS;
            int w = f - r * TWORDS;
            int gy = tiley - 15 + r;
            int gx = tilex - 15 + 2 * w;
            float v0 = 0.f, v1 = 0.f;
            if ((unsigned)gy < (unsigned)HH) {
                if ((unsigned)gx < (unsigned)WW) v0 = src[gy * WW + gx];
                if ((unsigned)(gx + 1) < (unsigned)WW) v1 = src[gy * WW + gx + 1];
            }
            h2_t pv; pv.x = (_Float16)v0; pv.y = (_Float16)v1;
            tile[f] = pv;
        }
    }

    __syncthreads();   // wtab + tile(ch0) staged

    // ---- (5) gather this thread's 4 weight rows into registers
    // even local col (j=0,2): phase A; odd (j=1,3): phase B (pre-shifted one tap)
    h2_t wj[4][16];
    #pragma unroll
    for (int j = 0; j < 4; ++j) {
        const h2_t* wp = &wtab[idx[j] * WSTR + (j & 1) * 16];
        #pragma unroll
        for (int m = 0; m < 4; ++m) {
            h8_t v = *(const h8_t*)(wp + 4 * m);   // 16B aligned: WSTR%4==0
            #pragma unroll
            for (int q = 0; q < 4; ++q) {
                h2_t t2; t2.x = v[2 * q]; t2.y = v[2 * q + 1];
                wj[j][4 * m + q] = t2;
            }
        }
    }

// word I (h2) view of a folded h4 buffer F[9] -- pure register aliasing
#define RWW(F, I) mkh2(F[(I) >> 1][((I) & 1) * 2], F[(I) >> 1][((I) & 1) * 2 + 1])

// issue one row's 9 ds_read_b64 into an h4 buffer
#define ISSUE_ROW(DST, ROW)                                                  \
    {                                                                        \
        _Pragma("unroll")                                                    \
        for (int m = 0; m < 9; ++m)                                          \
            DST[m] = *(const h4_t*)(rowbase + (ROW) * TWORDS + 2 * m);       \
    }

#define ISSUE_PAIR(QA, QB, D)                                                \
    ISSUE_ROW(QA, 15 - (D))                                                  \
    ISSUE_ROW(QB, 15 + (D))

// in-place fold: QA[m] += QB[m]  (2x v_pk_add_f16 each; QA becomes the row)
#define FOLD(QA, QB)                                                         \
    {                                                                        \
        _Pragma("unroll")                                                    \
        for (int m = 0; m < 9; ++m) QA[m] = QA[m] + QB[m];                   \
    }

// horizontal dot on folded buffer F (words 0..16 used; rs2/3 shifted by 1)
#define HDOTF(F, RS0, RS1, RS2, RS3)                                         \
    {                                                                        \
        _Pragma("unroll")                                                    \
        for (int m = 0; m < 16; ++m) {                                       \
            RS0 = __builtin_amdgcn_fdot2(wj[0][m], RWW(F, m),     RS0, false);\
            RS1 = __builtin_amdgcn_fdot2(wj[1][m], RWW(F, m),     RS1, false);\
            RS2 = __builtin_amdgcn_fdot2(wj[2][m], RWW(F, m + 1), RS2, false);\
            RS3 = __builtin_amdgcn_fdot2(wj[3][m], RWW(F, m + 1), RS3, false);\
        }                                                                    \
    }

// column-weight extraction for compile-time DY (verified phase mapping)
#define CWEXT(DY, CW0, CW1, CW2, CW3)                                        \
    {                                                                        \
        if (((DY) & 1) == 0) {                                               \
            CW0 = (float)wj[0][(DY) >> 1].x;                                 \
            CW2 = (float)wj[2][(DY) >> 1].x;                                 \
            CW1 = (float)wj[1][(DY) >> 1].y;                                 \
            CW3 = (float)wj[3][(DY) >> 1].y;                                 \
        } else {                                                             \
            CW0 = (float)wj[0][(DY) >> 1].y;                                 \
            CW2 = (float)wj[2][(DY) >> 1].y;                                 \
            CW1 = (float)wj[1][((DY) + 1) >> 1].x;                           \
            CW3 = (float)wj[3][((DY) + 1) >> 1].x;                           \
        }                                                                    \
    }

// pipeline step for pair D: fold cur, issue pair D+1, hdot cur (no fences)
#define STEP(D, CQA, CQB, NQA, NQB, DOISSUE)                                 \
    {                                                                        \
        FOLD(CQA, CQB)                                                       \
        if (DOISSUE) { ISSUE_PAIR(NQA, NQB, (D) + 1) }                       \
        float rs0 = 0.f, rs1 = 0.f, rs2 = 0.f, rs3 = 0.f;                    \
        HDOTF(CQA, rs0, rs1, rs2, rs3)                                       \
        float cw0, cw1, cw2, cw3;                                            \
        CWEXT(15 - (D), cw0, cw1, cw2, cw3)                                  \
        acc0 += cw0 * rs0;  acc1 += cw1 * rs1;                               \
        acc2 += cw2 * rs2;  acc3 += cw3 * rs3;                               \
    }

    // ---- (6) per-channel: compute c (pipelined dy-loop), then stage c+1
    #pragma unroll 1
    for (int c = 0; c < CC; ++c) {
        float acc0 = 0.f, acc1 = 0.f, acc2 = 0.f, acc3 = 0.f;
        const h2_t* rowbase = &tile[ty * TWORDS + 2 * tx];

        h4_t Aqa[9], Aqb[9], Bqa[9], Bqb[9];

        // prologue: center row reads + pair-1 reads in flight
        ISSUE_ROW(Aqa, 15)
        ISSUE_PAIR(Bqa, Bqb, 1)

        // center row (dy = 15): no fold, waits only on Aqa's 9 reads
        {
            float rs0 = 0.f, rs1 = 0.f, rs2 = 0.f, rs3 = 0.f;
            HDOTF(Aqa, rs0, rs1, rs2, rs3)
            float cw0, cw1, cw2, cw3;
            CWEXT(15, cw0, cw1, cw2, cw3)
            acc0 += cw0 * rs0;  acc1 += cw1 * rs1;
            acc2 += cw2 * rs2;  acc3 += cw3 * rs3;
        }

        STEP(1,  Bqa, Bqb, Aqa, Aqb, 1)
        STEP(2,  Aqa, Aqb, Bqa, Bqb, 1)
        STEP(3,  Bqa, Bqb, Aqa, Aqb, 1)
        STEP(4,  Aqa, Aqb, Bqa, Bqb, 1)
        STEP(5,  Bqa, Bqb, Aqa, Aqb, 1)
        STEP(6,  Aqa, Aqb, Bqa, Bqb, 1)
        STEP(7,  Bqa, Bqb, Aqa, Aqb, 1)
        STEP(8,  Aqa, Aqb, Bqa, Bqb, 1)
        STEP(9,  Bqa, Bqb, Aqa, Aqb, 1)
        STEP(10, Aqa, Aqb, Bqa, Bqb, 1)
        STEP(11, Bqa, Bqb, Aqa, Aqb, 1)
        STEP(12, Aqa, Aqb, Bqa, Bqb, 1)
        STEP(13, Bqa, Bqb, Aqa, Aqb, 1)
        STEP(14, Aqa, Aqb, Bqa, Bqb, 1)
        STEP(15, Bqa, Bqb, Aqa, Aqb, 0)

        *(float4*)&out[((size_t)(b * CC + c) * HH + yo) * WW + xo] =
            make_float4(acc0, acc1, acc2, acc3);

        if (c + 1 < CC) {
            __syncthreads();   // this channel's readers done
            const float* src = img + (size_t)(b * CC + c + 1) * HH * WW;
            for (int f = tid; f < TILEW; f += NT) {
                int r = f / TWORDS;
                int w = f - r * TWORDS;
                int gy = tiley - 15 + r;
                int gx = tilex - 15 + 2 * w;
                float v0 = 0.f, v1 = 0.f;
                if ((unsigned)gy < (unsigned)HH) {
                    if ((unsigned)gx < (unsigned)WW) v0 = src[gy * WW + gx];
                    if ((unsigned)(gx + 1) < (unsigned)WW) v1 = src[gy * WW + gx + 1];
                }
                h2_t pv; pv.x = (_Float16)v0; pv.y = (_Float16)v1;
                tile[f] = pv;
            }
            __syncthreads();   // tile(c+1) ready
        }
    }

#undef RWW
#undef ISSUE_ROW
#undef ISSUE_PAIR
#undef FOLD
#undef HDOTF
#undef CWEXT
#undef STEP
}

extern "C" void kernel_launch(void* const* d_in, const int* in_sizes, int n_in,
                              void* d_out, int out_size, void* d_ws, size_t ws_size,
                              hipStream_t stream) {
    const float* sharp = (const float*)d_in[0];
    const float* cocm  = (const float*)d_in[1];
    float* out = (float*)d_out;

    dim3 grid(WW / TXO, HH / TYO, BB);   // 8 x 32 x 4 = 1024 blocks
    dim3 block(16, 16, 1);
    defocus_kernel<<<grid, block, 0, stream>>>(sharp, cocm, out);
}